// Round 2
// baseline (423.440 us; speedup 1.0000x reference)
//
#include <hip/hip_runtime.h>

#define N_NODES 50000
#define N_EDGES 400000
#define IN_CH 1024
#define FEAT 128
#define NCOL 256   // concat of W_l (128) and W_r (128) outputs
#define HID 32
#define OUT_CH 3

#define BM 64
#define BK 32
#define LDT 40     // padded LDS stride in bf16 elems (80 B: 16B-aligned, 2-way bank alias = free)

typedef short bf16x8 __attribute__((ext_vector_type(8)));
typedef float f32x4 __attribute__((ext_vector_type(4)));

static __device__ __forceinline__ unsigned short f2bf(float x) {
  unsigned int u = __float_as_uint(x);
  return (unsigned short)((u + 0x7FFFu + ((u >> 16) & 1u)) >> 16);  // RNE
}

// ---- convert W_l,W_r (f32 [128][1024] each) into concat bf16 [256][1024]
__global__ void convert_w(const float* __restrict__ Wl, const float* __restrict__ Wr,
                          unsigned short* __restrict__ wbf) {
  for (int i = blockIdx.x * blockDim.x + threadIdx.x; i < NCOL * IN_CH;
       i += gridDim.x * blockDim.x) {
    int row = i >> 10;
    float v = (row < FEAT) ? Wl[i] : Wr[i - FEAT * IN_CH];
    wbf[i] = f2bf(v);
  }
}

// ---- Y[50000][256] = features @ Wcat^T  (bf16 MFMA, f32 accum)
__global__ __launch_bounds__(256) void gemm_y(const float* __restrict__ feat,
                                              const unsigned short* __restrict__ wbf,
                                              float* __restrict__ Y) {
  __shared__ __align__(16) unsigned short a_lds[BM * LDT];    // 5.0 KB
  __shared__ __align__(16) unsigned short b_lds[NCOL * LDT];  // 20 KB
  const int t = threadIdx.x;
  const int lane = t & 63;
  const int wc = t >> 6;          // wave id -> 64-col group
  const int r16 = lane & 15;
  const int kq = lane >> 4;       // k-quad 0..3
  const int blockRow = blockIdx.x * BM;

  f32x4 acc[4][4];
#pragma unroll
  for (int m = 0; m < 4; ++m)
#pragma unroll
    for (int n = 0; n < 4; ++n) acc[m][n] = (f32x4){0.f, 0.f, 0.f, 0.f};

  for (int k0 = 0; k0 < IN_CH; k0 += BK) {
    if (k0) __syncthreads();
    // stage A: 64 rows x 32 k of f32 -> bf16 LDS (2 float4 per thread)
#pragma unroll
    for (int i = 0; i < 2; ++i) {
      int f = t + i * 256;
      int row = f >> 3, c4 = f & 7;              // 8 chunks of 4 floats per row
      int gr = blockRow + row; gr = gr < N_NODES ? gr : N_NODES - 1;
      const float4 v = *(const float4*)(feat + (size_t)gr * IN_CH + k0 + c4 * 4);
      ushort4 u;
      u.x = f2bf(v.x); u.y = f2bf(v.y); u.z = f2bf(v.z); u.w = f2bf(v.w);
      *(ushort4*)(&a_lds[row * LDT + c4 * 4]) = u;
    }
    // stage B: 256 rows x 32 bf16 per row = 4 x 16B chunks per row
#pragma unroll
    for (int i = 0; i < 4; ++i) {
      int cch = t + i * 256;                     // 1024 chunks total
      int row = cch >> 2, q = cch & 3;           // 4 chunks of 8 shorts per row
      const uint4 v = *(const uint4*)(wbf + (size_t)row * IN_CH + k0 + q * 8);
      *(uint4*)(&b_lds[row * LDT + q * 8]) = v;
    }
    __syncthreads();
    bf16x8 av[4], bv[4];
#pragma unroll
    for (int m = 0; m < 4; ++m)
      av[m] = *(const bf16x8*)(&a_lds[(m * 16 + r16) * LDT + kq * 8]);
#pragma unroll
    for (int n = 0; n < 4; ++n)
      bv[n] = *(const bf16x8*)(&b_lds[(wc * 64 + n * 16 + r16) * LDT + kq * 8]);
#pragma unroll
    for (int m = 0; m < 4; ++m)
#pragma unroll
      for (int n = 0; n < 4; ++n)
        acc[m][n] = __builtin_amdgcn_mfma_f32_16x16x32_bf16(av[m], bv[n], acc[m][n], 0, 0, 0);
  }
  // store: row = blockRow + m*16 + kq*4 + reg ; col = wc*64 + n*16 + r16
#pragma unroll
  for (int m = 0; m < 4; ++m) {
#pragma unroll
    for (int reg = 0; reg < 4; ++reg) {
      int row = blockRow + m * 16 + kq * 4 + reg;
      if (row < N_NODES) {
#pragma unroll
        for (int n = 0; n < 4; ++n)
          Y[(size_t)row * NCOL + wc * 64 + n * 16 + r16] = acc[m][n][reg];
      }
    }
  }
}

// ---- scatter-add Y_l rows over edges (src -> dst), plus degree count
__global__ __launch_bounds__(256) void edge_agg(const int* __restrict__ e2,
                                                const float* __restrict__ Y,
                                                float* __restrict__ agg,
                                                float* __restrict__ cnt) {
  const int t = threadIdx.x;
  const int sub = t >> 7, c = t & 127;
  for (int e = blockIdx.x * 2 + sub; e < N_EDGES; e += gridDim.x * 2) {
    int src = e2[e];
    int dst = e2[N_EDGES + e];
    float v = Y[(size_t)src * NCOL + c];  // Y_l = cols 0..127
    atomicAdd(&agg[(size_t)dst * FEAT + c], v);
    if (c == 0) atomicAdd(&cnt[dst], 1.0f);
  }
}

// ---- per-node tail: mean + b_l + Y_r, leaky_relu, fc1+relu+bn, fc2
__global__ __launch_bounds__(256) void node_mlp(
    const float* __restrict__ Y, const float* __restrict__ agg, const float* __restrict__ cnt,
    const float* __restrict__ b_l, const float* __restrict__ fc1_w, const float* __restrict__ fc1_b,
    const float* __restrict__ fc2_w, const float* __restrict__ fc2_b,
    const float* __restrict__ gamma, const float* __restrict__ beta,
    const float* __restrict__ mean, const float* __restrict__ var,
    float* __restrict__ out) {
  __shared__ float xs[2][FEAT];
  __shared__ float hs[2][HID];
  const int t = threadIdx.x;
  const int g = t >> 7, c = t & 127;
  const int node = blockIdx.x * 2 + g;
  float rdeg = 1.0f / fmaxf(cnt[node], 1.0f);
  float x = agg[(size_t)node * FEAT + c] * rdeg + b_l[c] + Y[(size_t)node * NCOL + FEAT + c];
  x = x > 0.f ? x : 0.01f * x;  // leaky relu
  xs[g][c] = x;
  __syncthreads();
  if (c < HID) {
    float a = fc1_b[c];
    const float* wr = fc1_w + c * FEAT;
#pragma unroll 8
    for (int k = 0; k < FEAT; ++k) a += xs[g][k] * wr[k];
    a = fmaxf(a, 0.f);
    a = (a - mean[c]) * rsqrtf(var[c] + 1e-5f) * gamma[c] + beta[c];
    hs[g][c] = a;
  }
  __syncthreads();
  if (c < OUT_CH) {
    float o = fc2_b[c];
    const float* w2 = fc2_w + c * HID;
#pragma unroll
    for (int j = 0; j < HID; ++j) o += hs[g][j] * w2[j];
    out[node * 3 + c] = o;
  }
}

extern "C" void kernel_launch(void* const* d_in, const int* in_sizes, int n_in,
                              void* d_out, int out_size, void* d_ws, size_t ws_size,
                              hipStream_t stream) {
  const float* feat = (const float*)d_in[0];
  const int* e2 = (const int*)d_in[2];          // edges2 [2][400000] int32
  const float* Wl = (const float*)d_in[5];
  const float* bl = (const float*)d_in[6];
  const float* Wr = (const float*)d_in[7];
  const float* f1w = (const float*)d_in[8];
  const float* f1b = (const float*)d_in[9];
  const float* f2w = (const float*)d_in[10];
  const float* f2b = (const float*)d_in[11];
  const float* gma = (const float*)d_in[12];
  const float* bta = (const float*)d_in[13];
  const float* mu = (const float*)d_in[14];
  const float* var = (const float*)d_in[15];
  float* out = (float*)d_out;

  char* ws = (char*)d_ws;
  unsigned short* wbf = (unsigned short*)ws;                          // 512 KB
  float* Y = (float*)(ws + 524288);                                   // 51.2 MB
  float* agg = (float*)(ws + 524288 + 51200000);                      // 25.6 MB
  float* cnt = (float*)(ws + 524288 + 51200000 + 25600000);           // 200 KB

  hipMemsetAsync(agg, 0, (size_t)N_NODES * FEAT * sizeof(float), stream);
  hipMemsetAsync(cnt, 0, (size_t)N_NODES * sizeof(float), stream);
  convert_w<<<256, 256, 0, stream>>>(Wl, Wr, wbf);
  gemm_y<<<(N_NODES + BM - 1) / BM, 256, 0, stream>>>(feat, wbf, Y);
  edge_agg<<<2048, 256, 0, stream>>>(e2, Y, agg, cnt);
  node_mlp<<<N_NODES / 2, 256, 0, stream>>>(Y, agg, cnt, bl, f1w, f1b, f2w, f2b,
                                            gma, bta, mu, var, out);
}

// Round 3
// 406.939 us; speedup vs baseline: 1.0405x; 1.0405x over previous
//
#include <hip/hip_runtime.h>

#define N_NODES 50000
#define N_EDGES 400000
#define IN_CH 1024
#define FEAT 128
#define NCOL 256   // concat of W_l (128) and W_r (128) outputs
#define HID 32
#define OUT_CH 3

#define BM 64
#define BN 256
#define BK 64
#define LDA 72     // padded LDS stride (shorts): 36 words/row -> <=2-way bank alias (free)
#define LDB 72

typedef short bf16x8 __attribute__((ext_vector_type(8)));
typedef float f32x4 __attribute__((ext_vector_type(4)));

static __device__ __forceinline__ unsigned short f2bf(float x) {
  unsigned int u = __float_as_uint(x);
  return (unsigned short)((u + 0x7FFFu + ((u >> 16) & 1u)) >> 16);  // RNE
}

// ---- convert W_l,W_r (f32 [128][1024] each) into concat bf16 [256][1024]
__global__ void convert_w(const float* __restrict__ Wl, const float* __restrict__ Wr,
                          unsigned short* __restrict__ wbf) {
  for (int i = blockIdx.x * blockDim.x + threadIdx.x; i < NCOL * IN_CH;
       i += gridDim.x * blockDim.x) {
    int row = i >> 10;
    float v = (row < FEAT) ? Wl[i] : Wr[i - FEAT * IN_CH];
    wbf[i] = f2bf(v);
  }
}

// ---- Y[50000][256] = features @ Wcat^T  (bf16 MFMA, f32 accum, fused f32->bf16)
__global__ __launch_bounds__(256) void gemm_y(const float* __restrict__ feat,
                                              const unsigned short* __restrict__ wbf,
                                              float* __restrict__ Y) {
  __shared__ __align__(16) unsigned short a_lds[BM * LDA];   // 9 KB
  __shared__ __align__(16) unsigned short b_lds[BN * LDB];   // 36 KB
  const int t = threadIdx.x;
  const int lane = t & 63;
  const int w = t >> 6;           // wave -> 64-col group
  const int r16 = lane & 15;
  const int kq = lane >> 4;       // k-quad 0..3
  const int blockRow = blockIdx.x * BM;

  f32x4 acc[4][4];
#pragma unroll
  for (int m = 0; m < 4; ++m)
#pragma unroll
    for (int n = 0; n < 4; ++n) acc[m][n] = (f32x4){0.f, 0.f, 0.f, 0.f};

  for (int k0 = 0; k0 < IN_CH; k0 += BK) {
    if (k0) __syncthreads();
    // stage A: 64 rows x 64 k f32 -> bf16. 512 chunks of (8 f32 -> 16B bf16), 2/thread
#pragma unroll
    for (int i = 0; i < 2; ++i) {
      int id = i * 256 + t;
      int row = id >> 3, c8 = id & 7;
      int gr = blockRow + row; gr = gr < N_NODES ? gr : N_NODES - 1;
      const float4 f0 = *(const float4*)(feat + (size_t)gr * IN_CH + k0 + c8 * 8);
      const float4 f1 = *(const float4*)(feat + (size_t)gr * IN_CH + k0 + c8 * 8 + 4);
      bf16x8 u;
      u[0] = (short)f2bf(f0.x); u[1] = (short)f2bf(f0.y);
      u[2] = (short)f2bf(f0.z); u[3] = (short)f2bf(f0.w);
      u[4] = (short)f2bf(f1.x); u[5] = (short)f2bf(f1.y);
      u[6] = (short)f2bf(f1.z); u[7] = (short)f2bf(f1.w);
      *(bf16x8*)(&a_lds[row * LDA + c8 * 8]) = u;
    }
    // stage B: 256 rows x 64 k bf16 = 2048 x 16B chunks, 8/thread
#pragma unroll
    for (int i = 0; i < 8; ++i) {
      int id = i * 256 + t;
      int row = id >> 3, q = id & 7;
      const uint4 v = *(const uint4*)(wbf + (size_t)row * IN_CH + k0 + q * 8);
      *(uint4*)(&b_lds[row * LDB + q * 8]) = v;
    }
    __syncthreads();
#pragma unroll
    for (int ks = 0; ks < 2; ++ks) {
      bf16x8 av[4], bv[4];
#pragma unroll
      for (int m = 0; m < 4; ++m)
        av[m] = *(const bf16x8*)(&a_lds[(m * 16 + r16) * LDA + ks * 32 + kq * 8]);
#pragma unroll
      for (int n = 0; n < 4; ++n)
        bv[n] = *(const bf16x8*)(&b_lds[(w * 64 + n * 16 + r16) * LDB + ks * 32 + kq * 8]);
#pragma unroll
      for (int m = 0; m < 4; ++m)
#pragma unroll
        for (int n = 0; n < 4; ++n)
          acc[m][n] = __builtin_amdgcn_mfma_f32_16x16x32_bf16(av[m], bv[n], acc[m][n], 0, 0, 0);
    }
  }
  // store: row = blockRow + m*16 + kq*4 + reg ; col = w*64 + n*16 + r16
#pragma unroll
  for (int m = 0; m < 4; ++m) {
#pragma unroll
    for (int reg = 0; reg < 4; ++reg) {
      int row = blockRow + m * 16 + kq * 4 + reg;
      if (row < N_NODES) {
#pragma unroll
        for (int n = 0; n < 4; ++n)
          Y[(size_t)row * NCOL + w * 64 + n * 16 + r16] = acc[m][n][reg];
      }
    }
  }
}

// ---- CSR build: degree count
__global__ __launch_bounds__(256) void deg_kernel(const int* __restrict__ e2,
                                                  int* __restrict__ cnt) {
  int e = blockIdx.x * 256 + threadIdx.x;
  if (e < N_EDGES) atomicAdd(&cnt[e2[N_EDGES + e]], 1);
}

// ---- exclusive scan of cnt[50000] -> rowptr (single block, 1024 threads)
#define CHUNK 49  // ceil(50000/1024)
__global__ __launch_bounds__(1024) void scan_kernel(const int* __restrict__ cnt,
                                                    int* __restrict__ rowptr) {
  __shared__ int sums[1024];
  const int t = threadIdx.x;
  const int base = t * CHUNK;
  int s = 0;
#pragma unroll
  for (int i = 0; i < CHUNK; ++i) {
    int idx = base + i;
    if (idx < N_NODES) s += cnt[idx];
  }
  sums[t] = s;
  __syncthreads();
  if (t < 64) {
    int S = 0;
#pragma unroll
    for (int i = 0; i < 16; ++i) S += sums[t * 16 + i];
    int own = S;
    // inclusive scan across 64 lanes
#pragma unroll
    for (int off = 1; off < 64; off <<= 1) {
      int v = __shfl_up(S, off);
      if (t >= off) S += v;
    }
    int run = S - own;  // exclusive
#pragma unroll
    for (int i = 0; i < 16; ++i) {
      int tmp = sums[t * 16 + i];
      sums[t * 16 + i] = run;
      run += tmp;
    }
  }
  __syncthreads();
  int run = sums[t];
  for (int i = 0; i < CHUNK; ++i) {
    int idx = base + i;
    if (idx < N_NODES) {
      rowptr[idx] = run;
      run += cnt[idx];
    }
  }
  if (t == 0) rowptr[N_NODES] = N_EDGES;
}

// ---- CSR fill (cnt must be re-zeroed before this; used as cursor)
__global__ __launch_bounds__(256) void fill_kernel(const int* __restrict__ e2,
                                                   const int* __restrict__ rowptr,
                                                   int* __restrict__ cur,
                                                   int* __restrict__ csr_src) {
  int e = blockIdx.x * 256 + threadIdx.x;
  if (e < N_EDGES) {
    int src = e2[e];
    int dst = e2[N_EDGES + e];
    int pos = atomicAdd(&cur[dst], 1);
    csr_src[rowptr[dst] + pos] = src;
  }
}

// ---- fused gather-mean + SAGE combine + MLP tail. One wave per node.
__global__ __launch_bounds__(256) void gather_mlp(
    const int* __restrict__ rowptr, const int* __restrict__ csr_src,
    const float* __restrict__ Y, const float* __restrict__ b_l,
    const float* __restrict__ fc1_w, const float* __restrict__ fc1_b,
    const float* __restrict__ fc2_w, const float* __restrict__ fc2_b,
    const float* __restrict__ gamma, const float* __restrict__ beta,
    const float* __restrict__ mean, const float* __restrict__ var,
    float* __restrict__ out) {
  __shared__ float xs[4][FEAT];
  __shared__ float hs[4][HID];
  const int t = threadIdx.x;
  const int wid = t >> 6, lane = t & 63;
  const int n = blockIdx.x * 4 + wid;  // 12500*4 = 50000 exact

  const int start = rowptr[n], end = rowptr[n + 1];
  float a0 = 0.f, a1 = 0.f;
  int j = start;
  for (; j + 1 < end; j += 2) {
    int s0 = csr_src[j], s1 = csr_src[j + 1];
    const float* y0 = Y + (size_t)s0 * NCOL;
    const float* y1 = Y + (size_t)s1 * NCOL;
    float v00 = y0[lane], v01 = y0[64 + lane];
    float v10 = y1[lane], v11 = y1[64 + lane];
    a0 += v00 + v10;
    a1 += v01 + v11;
  }
  if (j < end) {
    int s0 = csr_src[j];
    a0 += Y[(size_t)s0 * NCOL + lane];
    a1 += Y[(size_t)s0 * NCOL + 64 + lane];
  }
  float rdeg = 1.0f / fmaxf((float)(end - start), 1.0f);
  float x0 = a0 * rdeg + b_l[lane] + Y[(size_t)n * NCOL + FEAT + lane];
  float x1 = a1 * rdeg + b_l[64 + lane] + Y[(size_t)n * NCOL + FEAT + 64 + lane];
  x0 = x0 > 0.f ? x0 : 0.01f * x0;
  x1 = x1 > 0.f ? x1 : 0.01f * x1;
  xs[wid][lane] = x0;
  xs[wid][64 + lane] = x1;
  __syncthreads();
  // fc1: 64 lanes = 32 hid units x 2 halves of the 128-dot
  {
    const int h = lane & 31, half = lane >> 5;
    const float* wr = fc1_w + h * FEAT + half * 64;
    const float* xv = xs[wid] + half * 64;
    float p = 0.f;
#pragma unroll 16
    for (int k = 0; k < 64; ++k) p += wr[k] * xv[k];
    p += __shfl_xor(p, 32);
    if (half == 0) {
      float a = p + fc1_b[h];
      a = fmaxf(a, 0.f);
      a = (a - mean[h]) * rsqrtf(var[h] + 1e-5f) * gamma[h] + beta[h];
      hs[wid][h] = a;
    }
  }
  __syncthreads();
  if (lane < OUT_CH) {
    float o = fc2_b[lane];
    const float* w2 = fc2_w + lane * HID;
#pragma unroll
    for (int k = 0; k < HID; ++k) o += hs[wid][k] * w2[k];
    out[n * 3 + lane] = o;
  }
}

extern "C" void kernel_launch(void* const* d_in, const int* in_sizes, int n_in,
                              void* d_out, int out_size, void* d_ws, size_t ws_size,
                              hipStream_t stream) {
  const float* feat = (const float*)d_in[0];
  const int* e2 = (const int*)d_in[2];          // edges2 [2][400000] int32
  const float* Wl = (const float*)d_in[5];
  const float* bl = (const float*)d_in[6];
  const float* Wr = (const float*)d_in[7];
  const float* f1w = (const float*)d_in[8];
  const float* f1b = (const float*)d_in[9];
  const float* f2w = (const float*)d_in[10];
  const float* f2b = (const float*)d_in[11];
  const float* gma = (const float*)d_in[12];
  const float* bta = (const float*)d_in[13];
  const float* mu = (const float*)d_in[14];
  const float* var = (const float*)d_in[15];
  float* out = (float*)d_out;

  char* ws = (char*)d_ws;
  unsigned short* wbf = (unsigned short*)ws;                  // 512 KB
  float* Y = (float*)(ws + (1 << 19));                        // 51.2 MB
  size_t off = (1 << 19) + (size_t)N_NODES * NCOL * 4;
  int* rowptr = (int*)(ws + off);                             // (N+1) ints
  off += (N_NODES + 1) * 4 + 4;
  int* cnt = (int*)(ws + off);                                // N ints (count / cursor)
  off += (size_t)N_NODES * 4;
  int* csr_src = (int*)(ws + off);                            // E ints

  const int EB = (N_EDGES + 255) / 256;
  hipMemsetAsync(cnt, 0, (size_t)N_NODES * 4, stream);
  deg_kernel<<<EB, 256, 0, stream>>>(e2, cnt);
  scan_kernel<<<1, 1024, 0, stream>>>(cnt, rowptr);
  hipMemsetAsync(cnt, 0, (size_t)N_NODES * 4, stream);
  fill_kernel<<<EB, 256, 0, stream>>>(e2, rowptr, cnt, csr_src);
  convert_w<<<256, 256, 0, stream>>>(Wl, Wr, wbf);
  gemm_y<<<(N_NODES + BM - 1) / BM, 256, 0, stream>>>(feat, wbf, Y);
  gather_mlp<<<N_NODES / 4, 256, 0, stream>>>(rowptr, csr_src, Y, bl, f1w, f1b,
                                              f2w, f2b, gma, bta, mu, var, out);
}

// Round 6
// 350.953 us; speedup vs baseline: 1.2065x; 1.1595x over previous
//
#include <hip/hip_runtime.h>
#include <hip/hip_bf16.h>

#define N_NODES 50000
#define N_EDGES 400000
#define IN_CH 1024
#define FEAT 128
#define NCOL 256
#define HID 32
#define OUT_CH 3

#define BM 256
#define BN 256
#define BK 64
#define LDA 72   // padded LDS stride (shorts): 36-word row stride -> 2-way bank alias (free)
#define LDB 72

typedef short bf16x8 __attribute__((ext_vector_type(8)));
typedef float f32x4 __attribute__((ext_vector_type(4)));

static __device__ __forceinline__ unsigned short f2bf(float x) {
  unsigned int u = __float_as_uint(x);
  return (unsigned short)((u + 0x7FFFu + ((u >> 16) & 1u)) >> 16);  // RNE
}
static __device__ __forceinline__ float bflo(unsigned v) { return __uint_as_float(v << 16); }
static __device__ __forceinline__ float bfhi(unsigned v) { return __uint_as_float(v & 0xFFFF0000u); }

// pack 8 f32 -> 8 bf16 (RNE via hw cvt)
static __device__ __forceinline__ bf16x8 cvt8(const float4 a, const float4 b) {
  __hip_bfloat162 p0 = __float22bfloat162_rn({a.x, a.y});
  __hip_bfloat162 p1 = __float22bfloat162_rn({a.z, a.w});
  __hip_bfloat162 p2 = __float22bfloat162_rn({b.x, b.y});
  __hip_bfloat162 p3 = __float22bfloat162_rn({b.z, b.w});
  bf16x8 u;
  u[0] = *(short*)&p0.x; u[1] = *(short*)&p0.y;
  u[2] = *(short*)&p1.x; u[3] = *(short*)&p1.y;
  u[4] = *(short*)&p2.x; u[5] = *(short*)&p2.y;
  u[6] = *(short*)&p3.x; u[7] = *(short*)&p3.y;
  return u;
}

// ---- convert W_l,W_r (f32 [128][1024] each) into concat bf16 [256][1024]
__global__ void convert_w(const float* __restrict__ Wl, const float* __restrict__ Wr,
                          unsigned short* __restrict__ wbf) {
  for (int i = blockIdx.x * blockDim.x + threadIdx.x; i < NCOL * IN_CH;
       i += gridDim.x * blockDim.x) {
    int row = i >> 10;
    float v = (row < FEAT) ? Wl[i] : Wr[i - FEAT * IN_CH];
    wbf[i] = f2bf(v);
  }
}

// ---- Ybf[50000][128] (bf16, = feat@W_l^T) and Yr[50000][128] (f32, = feat@W_r^T)
__global__ __launch_bounds__(512, 2) void gemm_y(const float* __restrict__ feat,
                                                 const unsigned short* __restrict__ wbf,
                                                 unsigned short* __restrict__ Ybf,
                                                 float* __restrict__ Yr) {
  __shared__ __align__(16) unsigned short a_lds[2][BM * LDA];  // 72 KB
  __shared__ __align__(16) unsigned short b_lds[2][BN * LDB];  // 72 KB
  const int t = threadIdx.x;
  const int lane = t & 63;
  const int w = t >> 6;
  const int wm = w >> 1, wn = w & 1;   // 4 M-waves x 2 N-waves
  const int r16 = lane & 15;
  const int kq = lane >> 4;
  const int R0 = blockIdx.x * BM;

  f32x4 acc[4][8];
#pragma unroll
  for (int m = 0; m < 4; ++m)
#pragma unroll
    for (int n = 0; n < 8; ++n) acc[m][n] = (f32x4){0.f, 0.f, 0.f, 0.f};

  float4 ra[4][2];  // A: 256 rows x 8 chunks (8 f32 each) = 2048 chunks, 4/thread
  uint4 rb[4];      // B: 256 rows x 8 chunks (8 bf16 each) = 2048 chunks, 4/thread

#define LOAD_TILE(K0)                                                                 \
  {                                                                                   \
    _Pragma("unroll") for (int i = 0; i < 4; ++i) {                                   \
      int p = i * 512 + t;                                                            \
      int row = p >> 3, c8 = p & 7;                                                   \
      int gr = R0 + row; gr = gr < N_NODES ? gr : N_NODES - 1;                        \
      const float4* src = (const float4*)(feat + (size_t)gr * IN_CH + (K0) + c8 * 8); \
      ra[i][0] = src[0]; ra[i][1] = src[1];                                           \
    }                                                                                 \
    _Pragma("unroll") for (int i = 0; i < 4; ++i) {                                   \
      int c = i * 512 + t;                                                            \
      int row = c >> 3, q = c & 7;                                                    \
      rb[i] = *(const uint4*)(wbf + (size_t)row * IN_CH + (K0) + q * 8);              \
    }                                                                                 \
  }

  LOAD_TILE(0);

  for (int it = 0; it < IN_CH / BK; ++it) {
    const int buf = it & 1;
#pragma unroll
    for (int i = 0; i < 4; ++i) {
      int p = i * 512 + t;
      int row = p >> 3, c8 = p & 7;
      *(bf16x8*)(&a_lds[buf][row * LDA + c8 * 8]) = cvt8(ra[i][0], ra[i][1]);
    }
#pragma unroll
    for (int i = 0; i < 4; ++i) {
      int c = i * 512 + t;
      int row = c >> 3, q = c & 7;
      *(uint4*)(&b_lds[buf][row * LDB + q * 8]) = rb[i];
    }
    if (it + 1 < IN_CH / BK) LOAD_TILE((it + 1) * BK);
    __syncthreads();
#pragma unroll
    for (int ks = 0; ks < 2; ++ks) {
      bf16x8 av[4], bv[8];
#pragma unroll
      for (int m = 0; m < 4; ++m)
        av[m] = *(const bf16x8*)(&a_lds[buf][(wm * 64 + m * 16 + r16) * LDA + ks * 32 + kq * 8]);
#pragma unroll
      for (int n = 0; n < 8; ++n)
        bv[n] = *(const bf16x8*)(&b_lds[buf][(wn * 128 + n * 16 + r16) * LDB + ks * 32 + kq * 8]);
#pragma unroll
      for (int m = 0; m < 4; ++m)
#pragma unroll
        for (int n = 0; n < 8; ++n)
          acc[m][n] = __builtin_amdgcn_mfma_f32_16x16x32_bf16(av[m], bv[n], acc[m][n], 0, 0, 0);
    }
    __syncthreads();
  }
#undef LOAD_TILE

  // epilogue: row = R0 + wm*64 + m*16 + kq*4 + reg; col = wn*128 + n*16 + r16
#pragma unroll
  for (int m = 0; m < 4; ++m) {
#pragma unroll
    for (int reg = 0; reg < 4; ++reg) {
      int row = R0 + wm * 64 + m * 16 + kq * 4 + reg;
      if (row < N_NODES) {
        if (wn == 0) {
#pragma unroll
          for (int n = 0; n < 8; ++n)
            Ybf[(size_t)row * FEAT + n * 16 + r16] = f2bf(acc[m][n][reg]);
        } else {
#pragma unroll
          for (int n = 0; n < 8; ++n)
            Yr[(size_t)row * FEAT + n * 16 + r16] = acc[m][n][reg];
        }
      }
    }
  }
}

// ---- CSR build
__global__ __launch_bounds__(256) void deg_kernel(const int* __restrict__ e2,
                                                  int* __restrict__ cnt) {
  int e = blockIdx.x * 256 + threadIdx.x;
  if (e < N_EDGES) atomicAdd(&cnt[e2[N_EDGES + e]], 1);
}

#define CHUNK 49  // ceil(50000/1024)
__global__ __launch_bounds__(1024) void scan_kernel(const int* __restrict__ cnt,
                                                    int* __restrict__ rowptr) {
  __shared__ int sums[1024];
  const int t = threadIdx.x;
  const int base = t * CHUNK;
  int s = 0;
#pragma unroll
  for (int i = 0; i < CHUNK; ++i) {
    int idx = base + i;
    if (idx < N_NODES) s += cnt[idx];
  }
  sums[t] = s;
  __syncthreads();
  if (t < 64) {
    int S = 0;
#pragma unroll
    for (int i = 0; i < 16; ++i) S += sums[t * 16 + i];
    int own = S;
#pragma unroll
    for (int off = 1; off < 64; off <<= 1) {
      int v = __shfl_up(S, off);
      if (t >= off) S += v;
    }
    int run = S - own;
#pragma unroll
    for (int i = 0; i < 16; ++i) {
      int tmp = sums[t * 16 + i];
      sums[t * 16 + i] = run;
      run += tmp;
    }
  }
  __syncthreads();
  int run = sums[t];
  for (int i = 0; i < CHUNK; ++i) {
    int idx = base + i;
    if (idx < N_NODES) {
      rowptr[idx] = run;
      run += cnt[idx];
    }
  }
  if (t == 0) rowptr[N_NODES] = N_EDGES;
}

__global__ __launch_bounds__(256) void fill_kernel(const int* __restrict__ e2,
                                                   const int* __restrict__ rowptr,
                                                   int* __restrict__ cur,
                                                   int* __restrict__ csr_src) {
  int e = blockIdx.x * 256 + threadIdx.x;
  if (e < N_EDGES) {
    int src = e2[e];
    int dst = e2[N_EDGES + e];
    int pos = atomicAdd(&cur[dst], 1);
    csr_src[rowptr[dst] + pos] = src;
  }
}

// ---- fused gather-mean + SAGE combine + MLP tail. One wave per node.
__global__ __launch_bounds__(256) void gather_mlp(
    const int* __restrict__ rowptr, const int* __restrict__ csr_src,
    const unsigned short* __restrict__ Ybf, const float* __restrict__ Yr,
    const float* __restrict__ b_l,
    const float* __restrict__ fc1_w, const float* __restrict__ fc1_b,
    const float* __restrict__ fc2_w, const float* __restrict__ fc2_b,
    const float* __restrict__ gamma, const float* __restrict__ beta,
    const float* __restrict__ mean, const float* __restrict__ var,
    float* __restrict__ out) {
  __shared__ float xs[4][FEAT];
  __shared__ float hs[4][HID];
  const int t = threadIdx.x;
  const int wid = t >> 6, lane = t & 63;
  const int n = blockIdx.x * 4 + wid;

  const int start = rowptr[n], end = rowptr[n + 1];
  float a0 = 0.f, a1 = 0.f;
  int j = start;
  for (; j + 3 < end; j += 4) {
    int s0 = csr_src[j], s1 = csr_src[j + 1], s2 = csr_src[j + 2], s3 = csr_src[j + 3];
    unsigned v0 = *(const unsigned*)(Ybf + (size_t)s0 * FEAT + 2 * lane);
    unsigned v1 = *(const unsigned*)(Ybf + (size_t)s1 * FEAT + 2 * lane);
    unsigned v2 = *(const unsigned*)(Ybf + (size_t)s2 * FEAT + 2 * lane);
    unsigned v3 = *(const unsigned*)(Ybf + (size_t)s3 * FEAT + 2 * lane);
    a0 += bflo(v0) + bflo(v1) + bflo(v2) + bflo(v3);
    a1 += bfhi(v0) + bfhi(v1) + bfhi(v2) + bfhi(v3);
  }
  for (; j < end; ++j) {
    unsigned v = *(const unsigned*)(Ybf + (size_t)csr_src[j] * FEAT + 2 * lane);
    a0 += bflo(v);
    a1 += bfhi(v);
  }
  float rdeg = 1.0f / fmaxf((float)(end - start), 1.0f);
  const float2 bl2 = *(const float2*)(b_l + 2 * lane);
  const float2 yr2 = *(const float2*)(Yr + (size_t)n * FEAT + 2 * lane);
  float x0 = a0 * rdeg + bl2.x + yr2.x;
  float x1 = a1 * rdeg + bl2.y + yr2.y;
  x0 = x0 > 0.f ? x0 : 0.01f * x0;
  x1 = x1 > 0.f ? x1 : 0.01f * x1;
  xs[wid][2 * lane] = x0;
  xs[wid][2 * lane + 1] = x1;
  __syncthreads();
  {
    const int h = lane & 31, half = lane >> 5;
    const float* wr = fc1_w + h * FEAT + half * 64;
    const float* xv = xs[wid] + half * 64;
    float p = 0.f;
#pragma unroll 16
    for (int k = 0; k < 64; ++k) p += wr[k] * xv[k];
    p += __shfl_xor(p, 32);
    if (half == 0) {
      float a = p + fc1_b[h];
      a = fmaxf(a, 0.f);
      a = (a - mean[h]) * rsqrtf(var[h] + 1e-5f) * gamma[h] + beta[h];
      hs[wid][h] = a;
    }
  }
  __syncthreads();
  if (lane < OUT_CH) {
    float o = fc2_b[lane];
    const float* w2 = fc2_w + lane * HID;
#pragma unroll
    for (int k = 0; k < HID; ++k) o += hs[wid][k] * w2[k];
    out[n * 3 + lane] = o;
  }
}

extern "C" void kernel_launch(void* const* d_in, const int* in_sizes, int n_in,
                              void* d_out, int out_size, void* d_ws, size_t ws_size,
                              hipStream_t stream) {
  const float* feat = (const float*)d_in[0];
  const int* e2 = (const int*)d_in[2];
  const float* Wl = (const float*)d_in[5];
  const float* bl = (const float*)d_in[6];
  const float* Wr = (const float*)d_in[7];
  const float* f1w = (const float*)d_in[8];
  const float* f1b = (const float*)d_in[9];
  const float* f2w = (const float*)d_in[10];
  const float* f2b = (const float*)d_in[11];
  const float* gma = (const float*)d_in[12];
  const float* bta = (const float*)d_in[13];
  const float* mu = (const float*)d_in[14];
  const float* var = (const float*)d_in[15];
  float* out = (float*)d_out;

  char* ws = (char*)d_ws;
  unsigned short* wbf = (unsigned short*)ws;                       // 512 KB
  unsigned short* Ybf = (unsigned short*)(ws + 524288);            // 12.8 MB
  float* Yr = (float*)(ws + 524288 + 12800000);                    // 25.6 MB
  size_t off = 524288 + 12800000 + 25600000;
  int* rowptr = (int*)(ws + off);                                  // (N+1) ints
  off += 200016;
  int* cnt = (int*)(ws + off);                                     // N ints
  off += 200000;
  int* csr_src = (int*)(ws + off);                                 // E ints

  const int EB = (N_EDGES + 255) / 256;
  hipMemsetAsync(cnt, 0, (size_t)N_NODES * 4, stream);
  deg_kernel<<<EB, 256, 0, stream>>>(e2, cnt);
  scan_kernel<<<1, 1024, 0, stream>>>(cnt, rowptr);
  hipMemsetAsync(cnt, 0, (size_t)N_NODES * 4, stream);
  fill_kernel<<<EB, 256, 0, stream>>>(e2, rowptr, cnt, csr_src);
  convert_w<<<256, 256, 0, stream>>>(Wl, Wr, wbf);
  gemm_y<<<(N_NODES + BM - 1) / BM, 512, 0, stream>>>(feat, wbf, Ybf, Yr);
  gather_mlp<<<N_NODES / 4, 256, 0, stream>>>(rowptr, csr_src, Ybf, Yr, bl,
                                              f1w, f1b, f2w, f2b, gma, bta, mu, var, out);
}

// Round 7
// 247.363 us; speedup vs baseline: 1.7118x; 1.4188x over previous
//
#include <hip/hip_runtime.h>
#include <hip/hip_bf16.h>

#define N_NODES 50000
#define N_EDGES 400000
#define IN_CH 1024
#define FEAT 128
#define HID 32
#define OUT_CH 3

#define BM 128
#define BK 32
#define LDA 40   // padded LDS stride (shorts): 80B rows, 16B-aligned
#define LDB 40

typedef short bf16x8 __attribute__((ext_vector_type(8)));
typedef float f32x4 __attribute__((ext_vector_type(4)));

static __device__ __forceinline__ unsigned short f2bf(float x) {
  unsigned int u = __float_as_uint(x);
  return (unsigned short)((u + 0x7FFFu + ((u >> 16) & 1u)) >> 16);  // RNE
}
static __device__ __forceinline__ float bflo(unsigned v) { return __uint_as_float(v << 16); }
static __device__ __forceinline__ float bfhi(unsigned v) { return __uint_as_float(v & 0xFFFF0000u); }

static __device__ __forceinline__ bf16x8 cvt8(const float4 a, const float4 b) {
  __hip_bfloat162 p0 = __float22bfloat162_rn({a.x, a.y});
  __hip_bfloat162 p1 = __float22bfloat162_rn({a.z, a.w});
  __hip_bfloat162 p2 = __float22bfloat162_rn({b.x, b.y});
  __hip_bfloat162 p3 = __float22bfloat162_rn({b.z, b.w});
  bf16x8 u;
  u[0] = *(short*)&p0.x; u[1] = *(short*)&p0.y;
  u[2] = *(short*)&p1.x; u[3] = *(short*)&p1.y;
  u[4] = *(short*)&p2.x; u[5] = *(short*)&p2.y;
  u[6] = *(short*)&p3.x; u[7] = *(short*)&p3.y;
  return u;
}

// ---- convert W_l,W_r (f32 [128][1024] each) into concat bf16 [256][1024]
__global__ void convert_w(const float* __restrict__ Wl, const float* __restrict__ Wr,
                          unsigned short* __restrict__ wbf) {
  for (int i = blockIdx.x * blockDim.x + threadIdx.x; i < 2 * FEAT * IN_CH;
       i += gridDim.x * blockDim.x) {
    int row = i >> 10;
    float v = (row < FEAT) ? Wl[i] : Wr[i - FEAT * IN_CH];
    wbf[i] = f2bf(v);
  }
}

// ---- Ybf[50000][128] (bf16 = feat@W_l^T), Yrbf[50000][128] (bf16 = feat@W_r^T)
__global__ __launch_bounds__(512, 4) void gemm_y(const float* __restrict__ feat,
                                                 const unsigned short* __restrict__ wbf,
                                                 unsigned short* __restrict__ Ybf,
                                                 unsigned short* __restrict__ Yrbf) {
  __shared__ __align__(16) unsigned short a_lds[2][BM * LDA];   // 20.5 KB
  __shared__ __align__(16) unsigned short b_lds[2][256 * LDB];  // 41 KB
  const int t = threadIdx.x;
  const int lane = t & 63;
  const int w = t >> 6;
  const int wm = w >> 1, wn = w & 1;   // 4 M-waves x 2 N-waves; wave tile 32x128
  const int r16 = lane & 15;
  const int kq = lane >> 4;
  const int R0 = blockIdx.x * BM;

  f32x4 acc[2][8];
#pragma unroll
  for (int m = 0; m < 2; ++m)
#pragma unroll
    for (int n = 0; n < 8; ++n) acc[m][n] = (f32x4){0.f, 0.f, 0.f, 0.f};

  const int arow = t >> 2, ac8 = t & 3;  // A: 128 rows x 4 chunks(8 f32); B: 2x that
  int gr = R0 + arow; gr = gr < N_NODES ? gr : N_NODES - 1;
  const float* abase = feat + (size_t)gr * IN_CH + ac8 * 8;
  const unsigned short* bbase0 = wbf + (size_t)arow * IN_CH + ac8 * 8;
  const unsigned short* bbase1 = wbf + (size_t)(128 + arow) * IN_CH + ac8 * 8;

  float4 ra0, ra1;
  uint4 rb0, rb1;

#define LOAD_TILE(K0)                              \
  {                                                \
    ra0 = *(const float4*)(abase + (K0));          \
    ra1 = *(const float4*)(abase + (K0) + 4);      \
    rb0 = *(const uint4*)(bbase0 + (K0));          \
    rb1 = *(const uint4*)(bbase1 + (K0));          \
  }

  LOAD_TILE(0);

  for (int it = 0; it < IN_CH / BK; ++it) {
    const int buf = it & 1;
    *(bf16x8*)(&a_lds[buf][arow * LDA + ac8 * 8]) = cvt8(ra0, ra1);
    *(uint4*)(&b_lds[buf][arow * LDB + ac8 * 8]) = rb0;
    *(uint4*)(&b_lds[buf][(128 + arow) * LDB + ac8 * 8]) = rb1;
    if (it + 1 < IN_CH / BK) LOAD_TILE((it + 1) * BK);
    __syncthreads();
    bf16x8 av[2];
#pragma unroll
    for (int m = 0; m < 2; ++m)
      av[m] = *(const bf16x8*)(&a_lds[buf][(wm * 32 + m * 16 + r16) * LDA + kq * 8]);
#pragma unroll
    for (int n = 0; n < 8; ++n) {
      bf16x8 bv = *(const bf16x8*)(&b_lds[buf][(wn * 128 + n * 16 + r16) * LDB + kq * 8]);
      acc[0][n] = __builtin_amdgcn_mfma_f32_16x16x32_bf16(av[0], bv, acc[0][n], 0, 0, 0);
      acc[1][n] = __builtin_amdgcn_mfma_f32_16x16x32_bf16(av[1], bv, acc[1][n], 0, 0, 0);
    }
    // no trailing barrier: buf it+1 != buf it; reuse of buf at it+2 is ordered
    // by the barrier at it+1 (all waves' MFMA reads complete before arriving).
  }
#undef LOAD_TILE

  unsigned short* dst = (wn == 0) ? Ybf : Yrbf;
#pragma unroll
  for (int m = 0; m < 2; ++m) {
#pragma unroll
    for (int reg = 0; reg < 4; ++reg) {
      int row = R0 + wm * 32 + m * 16 + kq * 4 + reg;
      if (row < N_NODES) {
#pragma unroll
        for (int n = 0; n < 8; ++n)
          dst[(size_t)row * FEAT + n * 16 + r16] = f2bf(acc[m][n][reg]);
      }
    }
  }
}

// ---- CSR build
__global__ __launch_bounds__(256) void deg_kernel(const int* __restrict__ e2,
                                                  int* __restrict__ cnt) {
  int e = blockIdx.x * 256 + threadIdx.x;
  if (e < N_EDGES) atomicAdd(&cnt[e2[N_EDGES + e]], 1);
}

#define CHUNK 49
__global__ __launch_bounds__(1024) void scan_kernel(const int* __restrict__ cnt,
                                                    int* __restrict__ rowptr) {
  __shared__ int sums[1024];
  const int t = threadIdx.x;
  const int base = t * CHUNK;
  int s = 0;
#pragma unroll
  for (int i = 0; i < CHUNK; ++i) {
    int idx = base + i;
    if (idx < N_NODES) s += cnt[idx];
  }
  sums[t] = s;
  __syncthreads();
  if (t < 64) {
    int S = 0;
#pragma unroll
    for (int i = 0; i < 16; ++i) S += sums[t * 16 + i];
    int own = S;
#pragma unroll
    for (int off = 1; off < 64; off <<= 1) {
      int v = __shfl_up(S, off);
      if (t >= off) S += v;
    }
    int run = S - own;
#pragma unroll
    for (int i = 0; i < 16; ++i) {
      int tmp = sums[t * 16 + i];
      sums[t * 16 + i] = run;
      run += tmp;
    }
  }
  __syncthreads();
  int run = sums[t];
  for (int i = 0; i < CHUNK; ++i) {
    int idx = base + i;
    if (idx < N_NODES) {
      rowptr[idx] = run;
      run += cnt[idx];
    }
  }
  if (t == 0) rowptr[N_NODES] = N_EDGES;
}

__global__ __launch_bounds__(256) void fill_kernel(const int* __restrict__ e2,
                                                   const int* __restrict__ rowptr,
                                                   int* __restrict__ cur,
                                                   int* __restrict__ csr_src) {
  int e = blockIdx.x * 256 + threadIdx.x;
  if (e < N_EDGES) {
    int src = e2[e];
    int dst = e2[N_EDGES + e];
    int pos = atomicAdd(&cur[dst], 1);
    csr_src[rowptr[dst] + pos] = src;
  }
}

// ---- fused gather-mean + SAGE combine + MLP tail. One wave per node, 8 nodes/wave.
#define NPB 32  // nodes per block (4 waves x 8)
__global__ __launch_bounds__(256) void gather_mlp(
    const int* __restrict__ rowptr, const int* __restrict__ csr_src,
    const unsigned short* __restrict__ Ybf, const unsigned short* __restrict__ Yrbf,
    const float* __restrict__ b_l,
    const float* __restrict__ fc1_w, const float* __restrict__ fc1_b,
    const float* __restrict__ fc2_w, const float* __restrict__ fc2_b,
    const float* __restrict__ gamma, const float* __restrict__ beta,
    const float* __restrict__ mean, const float* __restrict__ var,
    float* __restrict__ out) {
  __shared__ float wT[FEAT * 33];       // fc1_w transposed, stride 33: conflict-free
  __shared__ float xs[4][FEAT];
  __shared__ float hsb[4][HID];
  __shared__ float w2s[OUT_CH * HID];
  const int t = threadIdx.x;
  const int wid = t >> 6, lane = t & 63;

  // stage fc1_w^T: read coalesced, write stride-33 (banks spread)
  for (int idx = t; idx < HID * FEAT; idx += 256) {
    int h = idx >> 7, k = idx & 127;
    wT[k * 33 + h] = fc1_w[idx];
  }
  if (t < OUT_CH * HID) w2s[t] = fc2_w[t];
  const int h = lane & 31, half = lane >> 5;
  float bns, bnb, f1bh;
  {
    float g = gamma[h], mu = mean[h], v = var[h], b = beta[h];
    bns = g * rsqrtf(v + 1e-5f);
    bnb = b - mu * bns;
    f1bh = fc1_b[h];
  }
  const float2 bl2 = *(const float2*)(b_l + 2 * lane);
  __syncthreads();

  for (int i = 0; i < 8; ++i) {
    const int n = blockIdx.x * NPB + wid * 8 + i;
    if (n >= N_NODES) break;
    const int start = rowptr[n], end = rowptr[n + 1];
    float a0 = 0.f, a1 = 0.f;
    int j = start;
    for (; j + 3 < end; j += 4) {
      int s0 = csr_src[j], s1 = csr_src[j + 1], s2 = csr_src[j + 2], s3 = csr_src[j + 3];
      unsigned v0 = *(const unsigned*)(Ybf + (size_t)s0 * FEAT + 2 * lane);
      unsigned v1 = *(const unsigned*)(Ybf + (size_t)s1 * FEAT + 2 * lane);
      unsigned v2 = *(const unsigned*)(Ybf + (size_t)s2 * FEAT + 2 * lane);
      unsigned v3 = *(const unsigned*)(Ybf + (size_t)s3 * FEAT + 2 * lane);
      a0 += bflo(v0) + bflo(v1) + bflo(v2) + bflo(v3);
      a1 += bfhi(v0) + bfhi(v1) + bfhi(v2) + bfhi(v3);
    }
    for (; j < end; ++j) {
      unsigned v = *(const unsigned*)(Ybf + (size_t)csr_src[j] * FEAT + 2 * lane);
      a0 += bflo(v);
      a1 += bfhi(v);
    }
    const float rdeg = 1.0f / fmaxf((float)(end - start), 1.0f);
    const unsigned vy = *(const unsigned*)(Yrbf + (size_t)n * FEAT + 2 * lane);
    float x0 = a0 * rdeg + bl2.x + bflo(vy);
    float x1 = a1 * rdeg + bl2.y + bfhi(vy);
    x0 = x0 > 0.f ? x0 : 0.01f * x0;
    x1 = x1 > 0.f ? x1 : 0.01f * x1;
    // wave-private LDS: intra-wave ordering, no block barrier needed
    xs[wid][2 * lane] = x0;
    xs[wid][2 * lane + 1] = x1;
    float p = 0.f;
    const float* xv = xs[wid] + half * 64;
    const float* wv = wT + (half * 64) * 33 + h;
#pragma unroll 16
    for (int k = 0; k < 64; ++k) p += wv[k * 33] * xv[k];
    p += __shfl_xor(p, 32);
    if (half == 0) {
      float a = fmaxf(p + f1bh, 0.f);
      hsb[wid][h] = a * bns + bnb;
    }
    if (lane < OUT_CH) {
      float o = fc2_b[lane];
#pragma unroll
      for (int k2 = 0; k2 < HID; ++k2) o += hsb[wid][k2] * w2s[lane * HID + k2];
      out[n * 3 + lane] = o;
    }
  }
}

extern "C" void kernel_launch(void* const* d_in, const int* in_sizes, int n_in,
                              void* d_out, int out_size, void* d_ws, size_t ws_size,
                              hipStream_t stream) {
  const float* feat = (const float*)d_in[0];
  const int* e2 = (const int*)d_in[2];
  const float* Wl = (const float*)d_in[5];
  const float* bl = (const float*)d_in[6];
  const float* Wr = (const float*)d_in[7];
  const float* f1w = (const float*)d_in[8];
  const float* f1b = (const float*)d_in[9];
  const float* f2w = (const float*)d_in[10];
  const float* f2b = (const float*)d_in[11];
  const float* gma = (const float*)d_in[12];
  const float* bta = (const float*)d_in[13];
  const float* mu = (const float*)d_in[14];
  const float* var = (const float*)d_in[15];
  float* out = (float*)d_out;

  char* ws = (char*)d_ws;
  unsigned short* wbf = (unsigned short*)ws;                       // 512 KB
  unsigned short* Ybf = (unsigned short*)(ws + 524288);            // 12.8 MB
  unsigned short* Yrbf = (unsigned short*)(ws + 524288 + 12800000);// 12.8 MB
  size_t off = 524288 + 12800000 + 12800000;
  int* rowptr = (int*)(ws + off);                                  // (N+1) ints
  off += 200016;
  int* cnt = (int*)(ws + off);                                     // N ints
  off += 200000;
  int* csr_src = (int*)(ws + off);                                 // E ints

  const int EB = (N_EDGES + 255) / 256;
  hipMemsetAsync(cnt, 0, (size_t)N_NODES * 4, stream);
  deg_kernel<<<EB, 256, 0, stream>>>(e2, cnt);
  scan_kernel<<<1, 1024, 0, stream>>>(cnt, rowptr);
  hipMemsetAsync(cnt, 0, (size_t)N_NODES * 4, stream);
  fill_kernel<<<EB, 256, 0, stream>>>(e2, rowptr, cnt, csr_src);
  convert_w<<<256, 256, 0, stream>>>(Wl, Wr, wbf);
  gemm_y<<<(N_NODES + BM - 1) / BM, 512, 0, stream>>>(feat, wbf, Ybf, Yrbf);
  gather_mlp<<<(N_NODES + NPB - 1) / NPB, 256, 0, stream>>>(
      rowptr, csr_src, Ybf, Yrbf, bl, f1w, f1b, f2w, f2b, gma, bta, mu, var, out);
}